// Round 16
// baseline (47.492 us; speedup 1.0000x reference)
//
#include <hip/hip_runtime.h>
#include <hip/hip_bf16.h>

#define TT 2048
#define BATCH 8
#define MROWS (BATCH*TT)   // 16384
#define AW 8               // waves per attn block

typedef __attribute__((ext_vector_type(8))) short bf16x8;   // MFMA A/B frag (4 VGPR)
typedef __attribute__((ext_vector_type(4))) short s16x4;
typedef __attribute__((ext_vector_type(4))) float f32x4;    // MFMA C/D frag

__device__ __forceinline__ short f2bf(float f) {
    union { __hip_bfloat16 h; short s; } u;
    u.h = __float2bfloat16(f);
    return u.s;
}
__device__ __forceinline__ float bf2f(short s) {
    union { unsigned u; float f; } u;
    u.u = ((unsigned)(unsigned short)s) << 16;
    return u.f;
}

typedef __attribute__((address_space(3))) unsigned int       lds_u32_t;
typedef const __attribute__((address_space(1))) unsigned int g_u32_t;
__device__ __forceinline__ void gl_lds16(const void* g, void* l) {
    __builtin_amdgcn_global_load_lds((g_u32_t*)g, (lds_u32_t*)l, 16, 0, 0);
}

// ---------------------------------------------------------------------------
// W transpose: Wq|Wk|Wv [1024][64] f32 -> wt [192][1024] bf16 (row n = col of W)
// Wq gets scale = (1/32)*log2(e) folded in (softmax scale + exp->exp2).
// ---------------------------------------------------------------------------
__global__ __launch_bounds__(256) void wtrans_kernel(
    const float* __restrict__ Wk, const float* __restrict__ Wq,
    const float* __restrict__ Wv, short* __restrict__ wt)
{
    __shared__ float tile[64][68];
    const int mat = blockIdx.x >> 4;           // 0=q,1=k,2=v
    const int k0  = (blockIdx.x & 15) * 64;
    const float* W = (mat == 0) ? Wq : (mat == 1) ? Wk : Wv;
    const float scl = (mat == 0) ? 0.04508422002778011f : 1.0f;  // (1/32)*log2(e)
    const int t = threadIdx.x;
    const int row = t >> 2, quad = t & 3;
    #pragma unroll
    for (int i = 0; i < 4; i++) {
        float4 v = *(const float4*)(W + (size_t)(k0 + row) * 64 + quad * 16 + i * 4);
        *(float4*)&tile[row][quad * 16 + i * 4] = v;
    }
    __syncthreads();
    short tmp[16];
    #pragma unroll
    for (int j = 0; j < 16; j++) tmp[j] = f2bf(tile[quad * 16 + j][row] * scl);
    short* dst = wt + (size_t)(mat * 64 + row) * 1024 + k0 + quad * 16;
    #pragma unroll
    for (int j2 = 0; j2 < 2; j2++) {
        bf16x8 o;
        #pragma unroll
        for (int jj = 0; jj < 8; jj++) o[jj] = tmp[j2 * 8 + jj];
        *(bf16x8*)(dst + j2 * 8) = o;
    }
}

// ---------------------------------------------------------------------------
// Projection v5 (measured-best, R8/R15): BM=32, BN=192, BK=64, 256 thr, 512
// blocks (2/CU interleaved). Both operands staged via async global_load_lds
// (16B); XOR bank-swizzle via pre-swizzled per-lane GLOBAL source + swizzled
// LDS read (rule 21). 2-phase loop: stage(t+1) -> compute(t) -> barrier.
// ---------------------------------------------------------------------------
__global__ __launch_bounds__(256, 2) void proj_kernel(
    const float* __restrict__ x, const short* __restrict__ wt,
    short* __restrict__ qb, short* __restrict__ kb, short* __restrict__ vtb)
{
    // [0,16384): As [2][32][64] f32 (8192 B/buf)
    // [16384,65536): Bs [2][192][64] bf16 (24576 B/buf)
    __shared__ __align__(16) char lds[65536];

    const int tid  = threadIdx.x;
    const int lane = tid & 63, w = tid >> 6;
    const int l15  = lane & 15, g = lane >> 4;
    const int x7   = l15 & 7;
    const int wr   = w & 1;              // row group: rows wr*16..+15
    const int wc   = w >> 1;             // col group: cols wc*96..+95
    const int r0   = blockIdx.x * 32;

    // ---- staging addresses (per-lane global src pre-swizzled; LDS linear)
    const float* ag[2]; unsigned aOff[2];
    #pragma unroll
    for (int j = 0; j < 2; j++) {
        const int jp   = w * 2 + j;                 // issue 0..7, 4 rows each
        const int row  = jp * 4 + (lane >> 4);
        const int slot = (lane & 15) ^ (row & 7);
        ag[j]   = x + (size_t)(r0 + row) * 1024 + slot * 4;
        aOff[j] = jp * 1024;
    }
    const short* bg[6]; unsigned bOff[6];
    #pragma unroll
    for (int j = 0; j < 6; j++) {
        const int jp   = w * 6 + j;                 // issue 0..23, 8 rows each
        const int row  = jp * 8 + (lane >> 3);
        const int slot = (lane & 7) ^ (row & 7);
        bg[j]   = wt + (size_t)row * 1024 + slot * 8;
        bOff[j] = 16384 + jp * 1024;
    }

    f32x4 acc[6];
    #pragma unroll
    for (int nt = 0; nt < 6; nt++) acc[nt] = (f32x4){0.f, 0.f, 0.f, 0.f};

    // prologue: stage k-tile 0 into buffer 0
    #pragma unroll
    for (int j = 0; j < 2; j++) gl_lds16(ag[j], lds + aOff[j]);
    #pragma unroll
    for (int j = 0; j < 6; j++) gl_lds16(bg[j], lds + bOff[j]);
    __syncthreads();

    #pragma unroll
    for (int ks = 0; ks < 16; ks++) {
        const int cur = ks & 1;

        // issue async staging for next tile (lands by end-of-step barrier)
        if (ks < 15) {
            const int nb = cur ^ 1;
            #pragma unroll
            for (int j = 0; j < 2; j++)
                gl_lds16(ag[j] + (ks + 1) * 64, lds + nb * 8192 + aOff[j]);
            #pragma unroll
            for (int j = 0; j < 6; j++)
                gl_lds16(bg[j] + (ks + 1) * 64, lds + nb * 24576 + bOff[j]);
        }

        const float* Ab = (const float*)(lds + cur * 8192);
        const short* Bb = (const short*)(lds + 16384 + cur * 24576);

        // A frags: fp32 from LDS (swizzled slots), convert to bf16
        bf16x8 af[2];
        #pragma unroll
        for (int kc = 0; kc < 2; kc++) {
            const int arow = wr * 16 + l15;
            f32x4 lo = *(const f32x4*)(Ab + arow * 64 + ((kc * 8 + 2 * g)     ^ x7) * 4);
            f32x4 hi = *(const f32x4*)(Ab + arow * 64 + ((kc * 8 + 2 * g + 1) ^ x7) * 4);
            af[kc] = (bf16x8){ f2bf(lo[0]), f2bf(lo[1]), f2bf(lo[2]), f2bf(lo[3]),
                               f2bf(hi[0]), f2bf(hi[1]), f2bf(hi[2]), f2bf(hi[3]) };
        }
        // B frags (bf16, swizzled slots)
        bf16x8 bfr[6][2];
        #pragma unroll
        for (int nt = 0; nt < 6; nt++)
            #pragma unroll
            for (int kc = 0; kc < 2; kc++)
                bfr[nt][kc] = *(const bf16x8*)(
                    Bb + (wc * 96 + nt * 16 + l15) * 64 + ((kc * 4 + g) ^ x7) * 8);

        #pragma unroll
        for (int kc = 0; kc < 2; kc++)
            #pragma unroll
            for (int nt = 0; nt < 6; nt++)
                acc[nt] = __builtin_amdgcn_mfma_f32_16x16x32_bf16(
                    af[kc], bfr[nt][kc], acc[nt], 0, 0, 0);

        __syncthreads();
    }

    // ---- epilogue: q,k direct; v via LDS transpose (overlay on As region)
    const int bi  = r0 >> 11;
    const int sl0 = r0 & 2047;
    short* vsl = (short*)lds;            // [32][66]
    #pragma unroll
    for (int nt = 0; nt < 6; nt++) {
        const int c = wc * 96 + nt * 16 + l15;
        #pragma unroll
        for (int r = 0; r < 4; r++) {
            const int row = r0 + wr * 16 + g * 4 + r;
            const short v = f2bf(acc[nt][r]);
            if (c < 64)        qb[(size_t)row * 64 + c] = v;
            else if (c < 128)  kb[(size_t)row * 64 + (c - 64)] = v;
            else               vsl[(wr * 16 + g * 4 + r) * 66 + (c - 128)] = v;
        }
    }
    __syncthreads();
    {   // vt[b][col][seq]: thread owns (col, 8-seq segment)
        const int col = tid >> 2, seg = tid & 3;
        short tmp[8];
        #pragma unroll
        for (int j = 0; j < 8; j++) tmp[j] = vsl[(seg * 8 + j) * 66 + col];
        bf16x8 o;
        #pragma unroll
        for (int jj = 0; jj < 8; jj++) o[jj] = tmp[jj];
        *(bf16x8*)(vtb + ((size_t)bi * 64 + col) * TT + sl0 + seg * 8) = o;
    }
}

// ---------------------------------------------------------------------------
// Flash attention v5b: identical structure to measured-best v5 EXCEPT the
// kv-loop is unrolled by 2 with static ping-pong K buffers (kfA/kfB) —
// removes the 16x b128 register copy (64 v_mov/iter) the rolled loop needed.
// ---------------------------------------------------------------------------
__global__ __launch_bounds__(512, 2)
void attn_kernel(
    const short* __restrict__ qb, const short* __restrict__ kb,
    const short* __restrict__ vtb, float* __restrict__ out)
{
    __shared__ __align__(16) char smem[AW * 4608];
    __shared__ float ml[AW][64];   // [w][0..31]=m, [w][32..63]=l

    const int tid  = threadIdx.x;
    const int w    = tid >> 6, lane = tid & 63;
    const int l15  = lane & 15, g = lane >> 4;
    const int b    = blockIdx.x & 7;
    const int qt   = 63 - (blockIdx.x >> 3);
    const int r0   = qt * 32;
    const int nkv  = (r0 >> 6) + 1;

    short* ps = (short*)(smem + w * 4608);   // [32][72]

    const short* q  = qb  + (size_t)b * TT * 64;
    const short* k  = kb  + (size_t)b * TT * 64;
    const short* vt = vtb + (size_t)b * 64 * TT;

    bf16x8 qf[2][2];
    #pragma unroll
    for (int rt = 0; rt < 2; rt++)
        #pragma unroll
        for (int kc = 0; kc < 2; kc++)
            qf[rt][kc] = *(const bf16x8*)(q + (size_t)(r0 + rt * 16 + l15) * 64 + kc * 32 + g * 8);

    f32x4 o[2][4];
    float m_[2] = { -INFINITY, -INFINITY };
    float l_[2] = { 0.f, 0.f };
    #pragma unroll
    for (int rt = 0; rt < 2; rt++)
        #pragma unroll
        for (int ht = 0; ht < 4; ht++) o[rt][ht] = (f32x4){0.f, 0.f, 0.f, 0.f};

    bf16x8 kfA[4][2], kfB[4][2];

#define LOAD_K(DST, S0)                                                        \
    _Pragma("unroll")                                                          \
    for (int nt = 0; nt < 4; nt++)                                             \
        _Pragma("unroll")                                                      \
        for (int kc = 0; kc < 2; kc++)                                         \
            DST[nt][kc] = *(const bf16x8*)(                                    \
                k + (size_t)((S0) + nt * 16 + l15) * 64 + kc * 32 + g * 8);

#define ATTN_BODY(KF, KFN, T)                                                  \
    {                                                                          \
        const int s0   = (T) * 64;                                             \
        const bool diag = ((T) == nkv - 1);                                    \
        const bool more = ((T) + AW < nkv);                                    \
        f32x4 s[2][4];                                                         \
        _Pragma("unroll")                                                      \
        for (int rt = 0; rt < 2; rt++)                                         \
            _Pragma("unroll")                                                  \
            for (int nt = 0; nt < 4; nt++) s[rt][nt] = (f32x4){0.f,0.f,0.f,0.f}; \
        _Pragma("unroll")                                                      \
        for (int kc = 0; kc < 2; kc++)                                         \
            _Pragma("unroll")                                                  \
            for (int rt = 0; rt < 2; rt++)                                     \
                _Pragma("unroll")                                              \
                for (int nt = 0; nt < 4; nt++)                                 \
                    s[rt][nt] = __builtin_amdgcn_mfma_f32_16x16x32_bf16(       \
                        KF[nt][kc], qf[rt][kc], s[rt][nt], 0, 0, 0);           \
        bf16x8 vf[4][2];                                                       \
        _Pragma("unroll")                                                      \
        for (int ht = 0; ht < 4; ht++)                                         \
            _Pragma("unroll")                                                  \
            for (int kc = 0; kc < 2; kc++)                                     \
                vf[ht][kc] = *(const bf16x8*)(                                 \
                    vt + (size_t)(ht * 16 + l15) * TT + s0 + kc * 32 + g * 8); \
        if (more) { LOAD_K(KFN, s0 + AW * 64) }                                \
        if (diag) {                                                            \
            _Pragma("unroll")                                                  \
            for (int rt = 0; rt < 2; rt++) {                                   \
                const int qg = r0 + rt * 16 + l15;                             \
                _Pragma("unroll")                                              \
                for (int nt = 0; nt < 4; nt++)                                 \
                    _Pragma("unroll")                                          \
                    for (int r = 0; r < 4; r++)                                \
                        if (s0 + nt * 16 + g * 4 + r > qg) s[rt][nt][r] = -INFINITY; \
            }                                                                  \
        }                                                                      \
        _Pragma("unroll")                                                      \
        for (int rt = 0; rt < 2; rt++) {                                       \
            float a0 = fmaxf(fmaxf(s[rt][0][0], s[rt][0][1]), fmaxf(s[rt][0][2], s[rt][0][3])); \
            float a1 = fmaxf(fmaxf(s[rt][1][0], s[rt][1][1]), fmaxf(s[rt][1][2], s[rt][1][3])); \
            float a2 = fmaxf(fmaxf(s[rt][2][0], s[rt][2][1]), fmaxf(s[rt][2][2], s[rt][2][3])); \
            float a3 = fmaxf(fmaxf(s[rt][3][0], s[rt][3][1]), fmaxf(s[rt][3][2], s[rt][3][3])); \
            float tm = fmaxf(fmaxf(a0, a1), fmaxf(a2, a3));                    \
            tm = fmaxf(tm, __shfl_xor(tm, 16));                                \
            tm = fmaxf(tm, __shfl_xor(tm, 32));                                \
            const float mn = fmaxf(m_[rt], tm);                                \
            const float al = __builtin_amdgcn_exp2f(m_[rt] - mn);              \
            m_[rt] = mn;                                                       \
            _Pragma("unroll")                                                  \
            for (int nt = 0; nt < 4; nt++)                                     \
                _Pragma("unroll")                                              \
                for (int r = 0; r < 4; r++)                                    \
                    s[rt][nt][r] = __builtin_amdgcn_exp2f(s[rt][nt][r] - mn);  \
            float b0 = (s[rt][0][0] + s[rt][0][1]) + (s[rt][0][2] + s[rt][0][3]); \
            float b1 = (s[rt][1][0] + s[rt][1][1]) + (s[rt][1][2] + s[rt][1][3]); \
            float b2 = (s[rt][2][0] + s[rt][2][1]) + (s[rt][2][2] + s[rt][2][3]); \
            float b3 = (s[rt][3][0] + s[rt][3][1]) + (s[rt][3][2] + s[rt][3][3]); \
            float ts = (b0 + b1) + (b2 + b3);                                  \
            ts += __shfl_xor(ts, 16);                                          \
            ts += __shfl_xor(ts, 32);                                          \
            l_[rt] = l_[rt] * al + ts;                                         \
            float ab[4];                                                       \
            _Pragma("unroll")                                                  \
            for (int r = 0; r < 4; r++) ab[r] = __shfl(al, g * 4 + r);         \
            _Pragma("unroll")                                                  \
            for (int ht = 0; ht < 4; ht++)                                     \
                _Pragma("unroll")                                              \
                for (int r = 0; r < 4; r++)                                    \
                    o[rt][ht][r] *= ab[r];                                     \
            _Pragma("unroll")                                                  \
            for (int nt = 0; nt < 4; nt++) {                                   \
                s16x4 pk = { f2bf(s[rt][nt][0]), f2bf(s[rt][nt][1]),           \
                             f2bf(s[rt][nt][2]), f2bf(s[rt][nt][3]) };         \
                *(s16x4*)&ps[(rt * 16 + l15) * 72 + nt * 16 + g * 4] = pk;     \
            }                                                                  \
        }                                                                      \
        bf16x8 pf[2][2];                                                       \
        _Pragma("unroll")                                                      \
        for (int rt = 0; rt < 2; rt++)                                         \
            _Pragma("unroll")                                                  \
            for (int kc = 0; kc < 2; kc++)                                     \
                pf[rt][kc] = *(const bf16x8*)&ps[(rt * 16 + l15) * 72 + kc * 32 + g * 8]; \
        _Pragma("unroll")                                                      \
        for (int kc = 0; kc < 2; kc++)                                         \
            _Pragma("unroll")                                                  \
            for (int rt = 0; rt < 2; rt++)                                     \
                _Pragma("unroll")                                              \
                for (int ht = 0; ht < 4; ht++)                                 \
                    o[rt][ht] = __builtin_amdgcn_mfma_f32_16x16x32_bf16(       \
                        pf[rt][kc], vf[ht][kc], o[rt][ht], 0, 0, 0);           \
    }

    int t = w;
    if (t < nkv) {
        LOAD_K(kfA, t * 64)
        while (true) {
            ATTN_BODY(kfA, kfB, t)
            t += AW; if (t >= nkv) break;
            ATTN_BODY(kfB, kfA, t)
            t += AW; if (t >= nkv) break;
        }
    }
#undef ATTN_BODY
#undef LOAD_K

    if (g == 0) {
        #pragma unroll
        for (int rt = 0; rt < 2; rt++) {
            ml[w][rt * 16 + l15]      = m_[rt];
            ml[w][32 + rt * 16 + l15] = l_[rt];
        }
    }
    short* pO = ps;   // [32][68] bf16 (ps is dead now)
    #pragma unroll
    for (int rt = 0; rt < 2; rt++)
        #pragma unroll
        for (int ht = 0; ht < 4; ht++)
            #pragma unroll
            for (int r = 0; r < 4; r++)
                pO[(rt * 16 + g * 4 + r) * 68 + ht * 16 + l15] = f2bf(o[rt][ht][r]);
    __syncthreads();

    {
        const int row = tid >> 4, seg = tid & 15;
        float gm = -INFINITY;
        #pragma unroll
        for (int w2 = 0; w2 < AW; w2++) gm = fmaxf(gm, ml[w2][row]);
        float accL = 0.f;
        float accO[4] = {0.f, 0.f, 0.f, 0.f};
        #pragma unroll
        for (int w2 = 0; w2 < AW; w2++) {
            const float sc = __builtin_amdgcn_exp2f(ml[w2][row] - gm);
            accL = fmaf(sc, ml[w2][32 + row], accL);
            const s16x4 ov = *(const s16x4*)((const short*)(smem + w2 * 4608) + row * 68 + seg * 4);
            #pragma unroll
            for (int j = 0; j < 4; j++)
                accO[j] = fmaf(sc, bf2f(ov[j]), accO[j]);
        }
        const float inv = 1.f / accL;
        float4 res = make_float4(accO[0] * inv, accO[1] * inv, accO[2] * inv, accO[3] * inv);
        *(float4*)(out + ((size_t)b * TT + r0 + row) * 64 + seg * 4) = res;
    }
}

extern "C" void kernel_launch(void* const* d_in, const int* in_sizes, int n_in,
                              void* d_out, int out_size, void* d_ws, size_t ws_size,
                              hipStream_t stream) {
    const float* x  = (const float*)d_in[0];
    const float* Wk = (const float*)d_in[1];
    const float* Wq = (const float*)d_in[2];
    const float* Wv = (const float*)d_in[3];
    float* outp = (float*)d_out;

    short* wt  = (short*)d_ws;                     // [192][1024] bf16
    short* qb  = wt + (size_t)192 * 1024;          // [16384][64] bf16 (pre-scaled)
    short* kb  = qb + (size_t)MROWS * 64;          // [16384][64] bf16
    short* vtb = kb + (size_t)MROWS * 64;          // [8][64][2048] bf16 (V^T)

    wtrans_kernel<<<48, 256, 0, stream>>>(Wk, Wq, Wv, wt);
    proj_kernel<<<MROWS / 32, 256, 0, stream>>>(x, wt, qb, kb, vtb);
    attn_kernel<<<BATCH * 64, 512, 0, stream>>>(qb, kb, vtb, outp);
}